// Round 1
// baseline (6961.184 us; speedup 1.0000x reference)
//
#include <hip/hip_runtime.h>
#include <stdint.h>

// FPS: B=16, C=3, N=131072, M=2048. 256 blocks (16/batch) x 1024 thr, 1/CU.
//
// R7 = R6 + coordinate-carrying reduction (kills the post-barrier serial tail).
//  - R6 path after the global poll was: winner_s LDS broadcast + 2nd
//    __syncthreads + sel decode + dependent px/py/pz[sel] L2 loads
//    (~650-900 cy serial per round, 2048 rounds).
//  - R7: the winning lane already holds the winner's coords in VGPRs. Carry
//    them through: wave winner lane (unique: keys embed invIdx) writes
//    {key,x,y,z} to LDS; wave0 quad-reduces 16x4 words with payload and
//    publishes ONE coalesced 32 B store (lanes 0-3, self-tagged words:
//    w0=key|t<<49, w1..3=coord|t<<32). ALL 16 waves poll all 64 words
//    (512 B = 4 lines) and quad-reduce; coords arrive via 3x 32-bit shfl.
//    No winner_s, no 2nd barrier, no sel, no centroid loads at all.
//  - Distinct from failed R5: butterflies stay parallel across waves
//    (R5's regression was the wave0-serial tournament, VALUBusy 31->14%),
//    and publish is one coalesced 32 B store, not serialized words.
// Numerics (must bit-match XLA-CPU ref, as R2/R4/R5/R6):
//   d = fma(dz,dz, fma(dy,dy, dx*dx)); first-occurrence argmax via packed
//   key [distBits:32][invIdx:17]; carried coords are the original float
//   bits selected from registers => outputs bit-identical.

#define NBATCH    16
#define NPTS      131072
#define SUBBLOCKS 16
#define NTHREADS  1024
#define NWAVES    (NTHREADS / 64)
#define CHUNK     8192          // points per block
#define HALF      4096          // second group offset within chunk
#define SLOTW     4             // u64 words per block slot: key,x,y,z

typedef unsigned long long u64;

__device__ __forceinline__ u64 umax64(u64 a, u64 b) { return a > b ? a : b; }

__global__ __launch_bounds__(NTHREADS, 4)
void fps_kernel(const float* __restrict__ points,
                float* __restrict__ out,
                u64* __restrict__ slots, int M)
{
  __shared__ u64 W[NWAVES][SLOTW];   // per-wave winner {key,x,y,z}

  const int bid   = blockIdx.x;
  const int xcd   = bid & 7;                 // XCD swizzle (speed only)
  const int ord   = bid >> 3;
  const int batch = xcd * 2 + (ord >> 4);    // batch's 16 blocks share an XCD
  const int sub   = ord & 15;
  const int tid   = threadIdx.x;
  const int wave  = tid >> 6;
  const int lane  = tid & 63;
  const int role  = lane & 3;                // word within a slot

  const float* __restrict__ px = points + (size_t)batch * 3 * NPTS;
  const float* __restrict__ py = px + NPTS;
  const float* __restrict__ pz = px + 2 * NPTS;
  float* outb = out + (size_t)batch * 3 * M;
  u64* bslots = slots + (size_t)batch * 2 * SUBBLOCKS * SLOTW;

  const int cbase = sub * CHUNK;
  const int g0 = cbase + (tid << 2);         // global idx of first group
  const int g1 = g0 + HALF;                  // global idx of second group

  // Load this thread's 8 points (2 x float4 per coord plane, coalesced).
  float4 A0 = *(const float4*)(px + g0);
  float4 B0 = *(const float4*)(py + g0);
  float4 C0 = *(const float4*)(pz + g0);
  float4 A1 = *(const float4*)(px + g1);
  float4 B1 = *(const float4*)(py + g1);
  float4 C1 = *(const float4*)(pz + g1);
  float x0=A0.x, x1=A0.y, x2=A0.z, x3=A0.w, x4=A1.x, x5=A1.y, x6=A1.z, x7=A1.w;
  float y0=B0.x, y1=B0.y, y2=B0.z, y3=B0.w, y4=B1.x, y5=B1.y, y6=B1.z, y7=B1.w;
  float z0=C0.x, z1=C0.y, z2=C0.z, z3=C0.w, z4=C1.x, z5=C1.y, z6=C1.z, z7=C1.w;
  // Pin all 24 coords in VGPRs (R2/R3: compiler rematerializes otherwise).
  asm volatile("" :
    "+v"(x0),"+v"(x1),"+v"(x2),"+v"(x3),"+v"(x4),"+v"(x5),"+v"(x6),"+v"(x7),
    "+v"(y0),"+v"(y1),"+v"(y2),"+v"(y3),"+v"(y4),"+v"(y5),"+v"(y6),"+v"(y7),
    "+v"(z0),"+v"(z1),"+v"(z2),"+v"(z3),"+v"(z4),"+v"(z5),"+v"(z6),"+v"(z7));

  float d0, d1, d2, d3, d4, d5, d6, d7;
  d0 = d1 = d2 = d3 = d4 = d5 = d6 = d7 = __builtin_inff();

  // Selection 0 is index 0 by convention; centroid starts as point 0.
  float cx = px[0], cy = py[0], cz = pz[0];
  if (sub == 0 && tid == 0) {
    outb[0]     = cx;
    outb[M]     = cy;
    outb[2 * M] = cz;
  }

  for (int t = 1; t < M; ++t) {
    float best = -1.0f;
    int bidx = 0, bj = 0;
    // d = fma(dz,dz, fma(dy,dy, dx*dx)) : bit-matches the reference chain.
    // Ascending index order => strict '>' keeps the first (smallest) index.
#define STEP(XX, YY, ZZ, DREG, IDX, J) { \
    float dx = __fsub_rn((XX), cx); \
    float dy = __fsub_rn((YY), cy); \
    float dz = __fsub_rn((ZZ), cz); \
    float dd = __builtin_fmaf(dz, dz, __builtin_fmaf(dy, dy, __fmul_rn(dx, dx))); \
    DREG = DREG < dd ? DREG : dd; \
    if (DREG > best) { best = DREG; bidx = (IDX); bj = (J); } }
    STEP(x0, y0, z0, d0, g0 + 0, 0)
    STEP(x1, y1, z1, d1, g0 + 1, 1)
    STEP(x2, y2, z2, d2, g0 + 2, 2)
    STEP(x3, y3, z3, d3, g0 + 3, 3)
    STEP(x4, y4, z4, d4, g1 + 0, 4)
    STEP(x5, y5, z5, d5, g1 + 1, 5)
    STEP(x6, y6, z6, d6, g1 + 2, 6)
    STEP(x7, y7, z7, d7, g1 + 3, 7)

    // This thread's best-point coords (cndmask trees; independent of the
    // shuffle chain below, so the scheduler overlaps them with DS latency).
    float bx = bj==0?x0:bj==1?x1:bj==2?x2:bj==3?x3:bj==4?x4:bj==5?x5:bj==6?x6:x7;
    float by = bj==0?y0:bj==1?y1:bj==2?y2:bj==3?y3:bj==4?y4:bj==5?y5:bj==6?y6:y7;
    float bz = bj==0?z0:bj==1?z1:bj==2?z2:bj==3?z3:bj==4?z4:bj==5?z5:bj==6?z6:z7;

    // Pack [distBits:32 @17][invIdx:17 @0]; non-negative f32 bits are
    // order-preserving; invIdx breaks ties toward the SMALLEST index.
    u64 key = ((u64)__float_as_uint(best) << 17) | (u64)((NPTS - 1) - bidx);

    // Per-wave butterfly (parallel across all 16 waves).
    u64 wkey = key;
#pragma unroll
    for (int m = 32; m >= 1; m >>= 1) wkey = umax64(wkey, __shfl_xor(wkey, m, 64));

    // Unique winner lane (keys differ by invIdx) deposits key + coords.
    if (wkey == key) {
      W[wave][0] = key;
      W[wave][1] = (u64)__float_as_uint(bx);
      W[wave][2] = (u64)__float_as_uint(by);
      W[wave][3] = (u64)__float_as_uint(bz);
    }
    __syncthreads();   // the ONLY barrier per round

    u64* par = bslots + (size_t)(t & 1) * (SUBBLOCKS * SLOTW);

    if (wave == 0) {
      // Payload-carrying quad-reduce over 16 wave winners:
      // lane l owns word (l&3) of candidate (l>>2); butterfly over candidates.
      u64 mw = W[lane >> 2][role];
      u64 mk = W[lane >> 2][0];
#pragma unroll
      for (int m = 32; m >= 4; m >>= 1) {
        u64 ok = __shfl_xor(mk, m, 64);
        u64 ow = __shfl_xor(mw, m, 64);
        if (ok > mk) { mk = ok; mw = ow; }
      }
      // Publish: ONE coalesced 32 B store, every word self-tagged with t
      // (no ordering needed: poll validates all 64 tags before use).
      if (lane < 4) {
        u64 wd = (lane == 0) ? (((u64)t << 49) | mw)
                             : ((mw & 0xFFFFFFFFull) | ((u64)t << 32));
        __hip_atomic_store(par + (sub << 2) + lane, wd,
                           __ATOMIC_RELAXED, __HIP_MEMORY_SCOPE_AGENT);
      }
    }

    // ALL waves poll all 64 words (16 slots x 4): one 512 B coalesced read
    // per round; exit only when every word carries tag t.
    const u64* pp = par + lane;
    u64 v;
    for (;;) {
      v = __hip_atomic_load(pp, __ATOMIC_RELAXED, __HIP_MEMORY_SCOPE_AGENT);
      unsigned tag = (unsigned)(v >> (role ? 32 : 49));
      if (__ballot(tag == (unsigned)t) == ~0ull) break;
    }

    // Quad-reduce over the 16 block winners, carrying payload words.
    {
      u64 mk = __shfl(v, lane & 0x3C, 64) & 0x1FFFFFFFFFFFFull; // slot key, tag stripped
      u64 mw = v;
#pragma unroll
      for (int m = 32; m >= 4; m >>= 1) {
        u64 ok = __shfl_xor(mk, m, 64);
        u64 ow = __shfl_xor(mw, m, 64);
        if (ok > mk) { mk = ok; mw = ow; }
      }
      // Every quad now holds the winning slot's 4 words; pull coords from
      // the role-1/2/3 lanes of our own quad (32-bit shuffles).
      const int base = lane & 0x3C;
      unsigned lo = (unsigned)mw;
      cx = __uint_as_float((unsigned)__shfl((int)lo, base | 1, 64));
      cy = __uint_as_float((unsigned)__shfl((int)lo, base | 2, 64));
      cz = __uint_as_float((unsigned)__shfl((int)lo, base | 3, 64));
    }

    // Winner coords are the exact original float bits => bit-exact output.
    if (sub == 0 && tid == 0) {
      outb[t]         = cx;
      outb[M + t]     = cy;
      outb[2 * M + t] = cz;
    }
  }
}

extern "C" void kernel_launch(void* const* d_in, const int* in_sizes, int n_in,
                              void* d_out, int out_size, void* d_ws, size_t ws_size,
                              hipStream_t stream) {
  (void)in_sizes; (void)n_in; (void)ws_size;
  const float* points = (const float*)d_in[0];
  float* out = (float*)d_out;
  u64* slots = (u64*)d_ws;
  const int M = out_size / (NBATCH * 3);   // 2048

  // Zero barrier slots (stale tags must not alias t in 1..M-1).
  hipMemsetAsync(d_ws, 0,
                 (size_t)NBATCH * 2 * SUBBLOCKS * SLOTW * sizeof(u64), stream);

  hipLaunchKernelGGL(fps_kernel, dim3(NBATCH * SUBBLOCKS), dim3(NTHREADS), 0,
                     stream, points, out, slots, M);
}